// Round 10
// baseline (898.274 us; speedup 1.0000x reference)
//
#include <hip/hip_runtime.h>
#include <hip/hip_bf16.h>
#include <cstdint>

#define M_TOT 16384
#define K_TOT 4096
#define N_TOT 4096
#define RNK   16
#define BM 256
#define BN 256
#define BK 64
#define NTK (K_TOT / BK)   // 64 K-tiles

using bf16x8 = __attribute__((ext_vector_type(8))) __bf16;
using f32x4  = __attribute__((ext_vector_type(4))) float;

__device__ __forceinline__ unsigned short f2bf(float f) {
  union { float f; unsigned u; } v; v.f = f;
  unsigned u = v.u;
  unsigned r = (u + 0x7fffu + ((u >> 16) & 1u)) >> 16;
  return (unsigned short)r;
}

// ---------------- f32 -> bf16 conversion (W) --------------------------------
__global__ void cvt_f32_bf16(const float* __restrict__ in,
                             unsigned short* __restrict__ out, int n4) {
  int i = blockIdx.x * blockDim.x + threadIdx.x;
  int stride = gridDim.x * blockDim.x;
  for (; i < n4; i += stride) {
    float4 v = reinterpret_cast<const float4*>(in)[i];
    ushort4 o;
    o.x = f2bf(v.x); o.y = f2bf(v.y); o.z = f2bf(v.z); o.w = f2bf(v.w);
    reinterpret_cast<ushort4*>(out)[i] = o;
  }
}

// ------ fused: xb = bf16(x) (all lanes, vectorized) THEN inter from xb ------
__global__ __launch_bounds__(256) void xcvt_inter_kernel(
    const float* __restrict__ x, const int* __restrict__ eid,
    const float* __restrict__ la, unsigned short* __restrict__ xb,
    float* __restrict__ inter) {
  const int row0 = blockIdx.x * 8;
  const int t = threadIdx.x;

  const float4* xs = reinterpret_cast<const float4*>(x + (size_t)row0 * K_TOT);
  ushort4* xd = reinterpret_cast<ushort4*>(xb + (size_t)row0 * K_TOT);
#pragma unroll
  for (int i = 0; i < 32; ++i) {
    float4 v = xs[t + 256 * i];
    ushort4 o;
    o.x = f2bf(v.x); o.y = f2bf(v.y); o.z = f2bf(v.z); o.w = f2bf(v.w);
    xd[t + 256 * i] = o;
  }
  __syncthreads();   // compiler drains vmcnt(0) before the barrier

  const int e = eid[row0 >> 11];
  const int r = t >> 4;
  const int j = t & 15;
  const float* lar = la + ((size_t)e * RNK + r) * K_TOT;
  const unsigned short* xr = xb + (size_t)row0 * K_TOT;
  float acc[8] = {0.f,0.f,0.f,0.f,0.f,0.f,0.f,0.f};
  union bu { unsigned u; float f; };
  for (int c = 0; c < K_TOT / 128; ++c) {
    int k = c * 128 + j * 8;
    float4 la0 = *reinterpret_cast<const float4*>(lar + k);
    float4 la1 = *reinterpret_cast<const float4*>(lar + k + 4);
#pragma unroll
    for (int q = 0; q < 8; ++q) {
      uint4 u = *reinterpret_cast<const uint4*>(xr + (size_t)q * K_TOT + k);
      bu a, b;
      float s;
      a.u = u.x << 16; b.u = u.x & 0xffff0000u;
      s  = a.f * la0.x + b.f * la0.y;
      a.u = u.y << 16; b.u = u.y & 0xffff0000u;
      s += a.f * la0.z + b.f * la0.w;
      a.u = u.z << 16; b.u = u.z & 0xffff0000u;
      s += a.f * la1.x + b.f * la1.y;
      a.u = u.w << 16; b.u = u.w & 0xffff0000u;
      s += a.f * la1.z + b.f * la1.w;
      acc[q] += s;
    }
  }
#pragma unroll
  for (int q = 0; q < 8; ++q) {
    float a = acc[q];
    a += __shfl_xor(a, 1);
    a += __shfl_xor(a, 2);
    a += __shfl_xor(a, 4);
    a += __shfl_xor(a, 8);
    acc[q] = a;
  }
  if (j == 0) {
#pragma unroll
    for (int q = 0; q < 8; ++q)
      inter[(size_t)(row0 + q) * RNK + r] = acc[q];
  }
}

// ---------------- 256x256 8-phase bf16 GEMM + fused LoRA epilogue -----------
// De-pinned (round 10): no sched_barrier(0), no explicit lgkmcnt drains.
// The compiler's dependency-tracked counted lgkmcnt interleaves ds_read
// completion with MFMA issue (m97/m141 mechanism). Fenced raw barriers and
// counted vmcnt preserve the cross-wave staging hazard discipline.
#define GLD16(gsrc, ldst)                                                      \
  __builtin_amdgcn_global_load_lds(                                            \
      (__attribute__((address_space(1))) const void*)(gsrc),                   \
      (__attribute__((address_space(3))) void*)(ldst), 16, 0, 0)

#define FENCE() asm volatile("" ::: "memory")
#define BARRIER() do { FENCE(); __builtin_amdgcn_s_barrier(); FENCE(); } while (0)

// stage one K-half of A or B for tile T: 256 rows x 32 cols bf16 = 16KB, 2 GLD
#define STAGE(matB, kk, T) do {                                                \
  const int _b = (((T) & 1) << 16) + ((matB) << 15) + ((kk) << 14);            \
  const unsigned short* _g = (matB) ? gB : gA;                                 \
  const size_t _go = (size_t)(T) * BK + (size_t)(kk) * 32;                     \
  GLD16(_g + _go, smem + _b + ldsw);                                           \
  GLD16(_g + (size_t)128 * K_TOT + _go, smem + _b + 8192 + ldsw);              \
} while (0)

#define RD_A(DST, mh, kk, bo) do {                                             \
  _Pragma("unroll")                                                            \
  for (int i_ = 0; i_ < 4; ++i_)                                               \
    DST[i_] = *reinterpret_cast<const bf16x8*>(                                \
        smem + (bo) + ((kk) << 14) + aofs + (((mh) * 4 + i_) << 10));          \
} while (0)

#define RD_B(DST, kk, bo) do {                                                 \
  _Pragma("unroll")                                                            \
  for (int n_ = 0; n_ < 4; ++n_)                                               \
    DST[n_] = *reinterpret_cast<const bf16x8*>(                                \
        smem + (bo) + 32768 + ((kk) << 14) + bofs + (n_ << 10));               \
} while (0)

#define MMQ(ASET, BSET, mh) do {                                               \
  __builtin_amdgcn_s_setprio(1);                                               \
  _Pragma("unroll")                                                            \
  for (int i_ = 0; i_ < 4; ++i_) {                                             \
    _Pragma("unroll")                                                          \
    for (int n_ = 0; n_ < 4; ++n_)                                             \
      acc[(mh) * 4 + i_][n_] = __builtin_amdgcn_mfma_f32_16x16x32_bf16(        \
          ASET[i_], BSET[n_], acc[(mh) * 4 + i_][n_], 0, 0, 0);                \
  }                                                                            \
  __builtin_amdgcn_s_setprio(0);                                               \
} while (0)

__global__ __launch_bounds__(512, 2) void gemm_kernel(
    const unsigned short* __restrict__ xb, const unsigned short* __restrict__ wb,
    const float* __restrict__ bias, const float* __restrict__ inter,
    const float* __restrict__ lb, const int* __restrict__ eid,
    float* __restrict__ out) {
  __shared__ unsigned char smem[131072];

  const int bid = blockIdx.x;
  const int swz = (bid & 7) * 128 + (bid >> 3);   // 1024 wgs, bijective
  const int bm = swz >> 4, bn = swz & 15;         // bm-major (r7 map, best FETCH)
  const int brow = bm * BM, bcol = bn * BN;
  const int t = threadIdx.x;
  const int w = t >> 6, l = t & 63;
  const int wr = w >> 2, wc = w & 3;              // 2 x 4 wave grid, wave = 128x64 out
  const int lr = l & 15;

  // staging source (pre-swizzled; inverse of the ds_read swizzle, rule 21).
  // f(row) = (row>>1)&3; GLD row = t>>2  ->  f = (t>>3)&3.
  const int srow = t >> 2;
  const int scol = ((t & 3) ^ ((t >> 3) & 3)) << 3;
  const unsigned short* gA = xb + (size_t)(brow + srow) * K_TOT + scol;
  const unsigned short* gB = wb + (size_t)(bcol + srow) * K_TOT + scol;
  const int ldsw = w << 10;

  // ds_read swizzle: 16B slot = (l>>4) ^ f(row), f(row) = (row>>1)&3.
  // Bank-start = 16*(row&1) + 4*slot: within any 8 consecutive lanes all 8
  // bank-quads are hit exactly once -> conflict-free ds_read_b128.
  const int s4 = (((l >> 4) ^ ((lr >> 1) & 3)) << 4);
  const int aofs = wr * 8192 + lr * 64 + s4;
  const int bofs = wc * 4096 + lr * 64 + s4;

  f32x4 acc[8][4];
#pragma unroll
  for (int i = 0; i < 8; ++i)
#pragma unroll
    for (int n = 0; n < 4; ++n)
      acc[i][n] = (f32x4){0.f, 0.f, 0.f, 0.f};
  bf16x8 A0[4], A1[4], B0[4], B1[4];

  // prologue: tile0 all 4 halves + tile1 {B-k0, A-k0, B-k1}; keep T1's 3
  // halves (6 instr) in flight across the barrier (T4: counted vmcnt).
  STAGE(0, 0, 0); STAGE(1, 0, 0); STAGE(0, 1, 0); STAGE(1, 1, 0);
  STAGE(1, 0, 1); STAGE(0, 0, 1); STAGE(1, 1, 1);
  asm volatile("s_waitcnt vmcnt(6)" ::: "memory");
  BARRIER();

  for (int T = 0; T < NTK; ++T) {
    const int bo = (T & 1) << 16;
    // ph0: reads for this phase ; stage A-k1(T+1)
    RD_A(A0, 0, 0, bo); RD_B(B0, 0, bo);
    if (T + 1 < NTK) STAGE(0, 1, T + 1);
    BARRIER();
    MMQ(A0, B0, 0);
    BARRIER();
    // ph1: stage B-k0(T+2)
    RD_A(A1, 1, 0, bo);
    if (T + 2 < NTK) STAGE(1, 0, T + 2);
    BARRIER();
    MMQ(A1, B0, 1);
    BARRIER();
    // ph2: stage A-k0(T+2)
    RD_A(A0, 0, 1, bo); RD_B(B1, 1, bo);
    if (T + 2 < NTK) STAGE(0, 0, T + 2);
    BARRIER();
    MMQ(A0, B1, 0);
    BARRIER();
    // ph3: stage B-k1(T+2) ; boundary: retire exactly tile T+1's 4 halves,
    // keep T+2's 3 halves (6 instr) in flight.
    RD_A(A1, 1, 1, bo);
    if (T + 2 < NTK) STAGE(1, 1, T + 2);
    BARRIER();
    MMQ(A1, B1, 1);
    if (T + 2 < NTK) { asm volatile("s_waitcnt vmcnt(6)" ::: "memory"); }
    else             { asm volatile("s_waitcnt vmcnt(0)" ::: "memory"); }
    BARRIER();
  }

  // ---------------- epilogue: bias + 2.0 * inter @ lb^T ----------------
  __syncthreads();
  float* interS = reinterpret_cast<float*>(smem);           // 256 x 16 f32 (broadcast)
  float* lbS    = reinterpret_cast<float*>(smem + 16384);   // 256 x 17 f32 (padded)
  const int e = eid[brow >> 11];
  const float* interG = inter + (size_t)brow * RNK;
  const float* lbG    = lb + ((size_t)e * N_TOT + bcol) * RNK;
#pragma unroll
  for (int q = 0; q < 8; ++q) {
    const int idx = t + 512 * q;
    interS[idx] = interG[idx];
    lbS[(idx >> 4) * 17 + (idx & 15)] = lbG[idx];
  }
  __syncthreads();

  float bv[4];
#pragma unroll
  for (int n = 0; n < 4; ++n)
    bv[n] = bias[bcol + wc * 64 + n * 16 + lr];

#pragma unroll
  for (int mi = 0; mi < 8; ++mi) {
#pragma unroll
    for (int j = 0; j < 4; ++j) {
      const int ml = wr * 128 + mi * 16 + (l >> 4) * 4 + j;
      const float* iv = interS + ml * RNK;
      const size_t orow = (size_t)(brow + ml) * N_TOT + bcol;
#pragma unroll
      for (int n = 0; n < 4; ++n) {
        const int ol = wc * 64 + n * 16 + lr;
        const float* lv = lbS + ol * 17;
        float d = 0.f;
#pragma unroll
        for (int r = 0; r < RNK; ++r) d += iv[r] * lv[r];
        out[orow + ol] = acc[mi][n][j] + bv[n] + 2.0f * d;
      }
    }
  }
}

extern "C" void kernel_launch(void* const* d_in, const int* in_sizes, int n_in,
                              void* d_out, int out_size, void* d_ws, size_t ws_size,
                              hipStream_t stream) {
  const float* x    = (const float*)d_in[0];
  const int*   eid  = (const int*)d_in[1];
  const float* W    = (const float*)d_in[2];
  const float* bias = (const float*)d_in[3];
  const float* la   = (const float*)d_in[4];
  const float* lb   = (const float*)d_in[5];
  float* out = (float*)d_out;

  // workspace layout: xb (134MB) | wb (33.5MB) | inter (1MB)
  unsigned short* xb = (unsigned short*)d_ws;
  unsigned short* wb = xb + (size_t)M_TOT * K_TOT;
  float* inter = (float*)(wb + (size_t)N_TOT * K_TOT);

  cvt_f32_bf16<<<2048, 256, 0, stream>>>(W, wb, (N_TOT * K_TOT) / 4);
  xcvt_inter_kernel<<<M_TOT / 8, 256, 0, stream>>>(x, eid, la, xb, inter);

  gemm_kernel<<<(M_TOT / BM) * (N_TOT / BN), 512, 0, stream>>>(
      xb, wb, bias, inter, lb, eid, out);
}

// Round 11
// 792.328 us; speedup vs baseline: 1.1337x; 1.1337x over previous
//
#include <hip/hip_runtime.h>
#include <hip/hip_bf16.h>
#include <cstdint>

#define M_TOT 16384
#define K_TOT 4096
#define N_TOT 4096
#define RNK   16
#define BM 256
#define BN 256
#define BK 64
#define NTK (K_TOT / BK)   // 64 K-tiles

using bf16x8 = __attribute__((ext_vector_type(8))) __bf16;
using f32x16 = __attribute__((ext_vector_type(16))) float;

__device__ __forceinline__ unsigned short f2bf(float f) {
  union { float f; unsigned u; } v; v.f = f;
  unsigned u = v.u;
  unsigned r = (u + 0x7fffu + ((u >> 16) & 1u)) >> 16;
  return (unsigned short)r;
}

// ---------------- f32 -> bf16 conversion (W) --------------------------------
__global__ void cvt_f32_bf16(const float* __restrict__ in,
                             unsigned short* __restrict__ out, int n4) {
  int i = blockIdx.x * blockDim.x + threadIdx.x;
  int stride = gridDim.x * blockDim.x;
  for (; i < n4; i += stride) {
    float4 v = reinterpret_cast<const float4*>(in)[i];
    ushort4 o;
    o.x = f2bf(v.x); o.y = f2bf(v.y); o.z = f2bf(v.z); o.w = f2bf(v.w);
    reinterpret_cast<ushort4*>(out)[i] = o;
  }
}

// ------ fused: xb = bf16(x) (all lanes, vectorized) THEN inter from xb ------
__global__ __launch_bounds__(256) void xcvt_inter_kernel(
    const float* __restrict__ x, const int* __restrict__ eid,
    const float* __restrict__ la, unsigned short* __restrict__ xb,
    float* __restrict__ inter) {
  const int row0 = blockIdx.x * 8;
  const int t = threadIdx.x;

  const float4* xs = reinterpret_cast<const float4*>(x + (size_t)row0 * K_TOT);
  ushort4* xd = reinterpret_cast<ushort4*>(xb + (size_t)row0 * K_TOT);
#pragma unroll
  for (int i = 0; i < 32; ++i) {
    float4 v = xs[t + 256 * i];
    ushort4 o;
    o.x = f2bf(v.x); o.y = f2bf(v.y); o.z = f2bf(v.z); o.w = f2bf(v.w);
    xd[t + 256 * i] = o;
  }
  __syncthreads();   // compiler drains vmcnt(0) before the barrier

  const int e = eid[row0 >> 11];
  const int r = t >> 4;
  const int j = t & 15;
  const float* lar = la + ((size_t)e * RNK + r) * K_TOT;
  const unsigned short* xr = xb + (size_t)row0 * K_TOT;
  float acc[8] = {0.f,0.f,0.f,0.f,0.f,0.f,0.f,0.f};
  union bu { unsigned u; float f; };
  for (int c = 0; c < K_TOT / 128; ++c) {
    int k = c * 128 + j * 8;
    float4 la0 = *reinterpret_cast<const float4*>(lar + k);
    float4 la1 = *reinterpret_cast<const float4*>(lar + k + 4);
#pragma unroll
    for (int q = 0; q < 8; ++q) {
      uint4 u = *reinterpret_cast<const uint4*>(xr + (size_t)q * K_TOT + k);
      bu a, b;
      float s;
      a.u = u.x << 16; b.u = u.x & 0xffff0000u;
      s  = a.f * la0.x + b.f * la0.y;
      a.u = u.y << 16; b.u = u.y & 0xffff0000u;
      s += a.f * la0.z + b.f * la0.w;
      a.u = u.z << 16; b.u = u.z & 0xffff0000u;
      s += a.f * la1.x + b.f * la1.y;
      a.u = u.w << 16; b.u = u.w & 0xffff0000u;
      s += a.f * la1.z + b.f * la1.w;
      acc[q] += s;
    }
  }
#pragma unroll
  for (int q = 0; q < 8; ++q) {
    float a = acc[q];
    a += __shfl_xor(a, 1);
    a += __shfl_xor(a, 2);
    a += __shfl_xor(a, 4);
    a += __shfl_xor(a, 8);
    acc[q] = a;
  }
  if (j == 0) {
#pragma unroll
    for (int q = 0; q < 8; ++q)
      inter[(size_t)(row0 + q) * RNK + r] = acc[q];
  }
}

// ---------- 256x256 8-phase GEMM, 32x32x16 MFMA + fused LoRA epilogue -------
#define GLD16(gsrc, ldst)                                                      \
  __builtin_amdgcn_global_load_lds(                                            \
      (__attribute__((address_space(1))) const void*)(gsrc),                   \
      (__attribute__((address_space(3))) void*)(ldst), 16, 0, 0)

#define FENCE() asm volatile("" ::: "memory")
#define BARRIER() do { FENCE(); __builtin_amdgcn_s_barrier(); FENCE(); } while (0)

// stage one K-half of A or B for tile T: 256 rows x 32 cols bf16 = 16KB, 2 GLD
#define STAGE(matB, kk, T) do {                                                \
  const int _b = (((T) & 1) << 16) + ((matB) << 15) + ((kk) << 14);            \
  const unsigned short* _g = (matB) ? gB : gA;                                 \
  const size_t _go = (size_t)(T) * BK + (size_t)(kk) * 32;                     \
  GLD16(_g + _go, smem + _b + ldsw);                                           \
  GLD16(_g + (size_t)128 * K_TOT + _go, smem + _b + 8192 + ldsw);              \
} while (0)

// A fragments for 32x32x16: lane wants row R = wr*128 + ar*32 + (l&31),
// k8-block s = ks*2 + (l>>5); chunk(R>>4) of 1KB, 64B rows, swizzled 16B slot.
#define RD_A32(DST, mh, kk, bo) do {                                           \
  _Pragma("unroll")                                                            \
  for (int a_ = 0; a_ < 2; ++a_)                                               \
    _Pragma("unroll")                                                          \
    for (int ks_ = 0; ks_ < 2; ++ks_)                                          \
      DST[a_][ks_] = *reinterpret_cast<const bf16x8*>(                         \
          smem + (bo) + ((kk) << 14) +                                         \
          ((wr * 8 + ((mh) * 2 + a_) * 2 + lhi) << 10) + l15 * 64 +            \
          ((((ks_ << 1) + l32) ^ lsw) << 4));                                  \
} while (0)

#define RD_B32(DST, kk, bo) do {                                               \
  _Pragma("unroll")                                                            \
  for (int n_ = 0; n_ < 2; ++n_)                                               \
    _Pragma("unroll")                                                          \
    for (int ks_ = 0; ks_ < 2; ++ks_)                                          \
      DST[n_][ks_] = *reinterpret_cast<const bf16x8*>(                         \
          smem + (bo) + 32768 + ((kk) << 14) +                                 \
          ((wc * 4 + n_ * 2 + lhi) << 10) + l15 * 64 +                         \
          ((((ks_ << 1) + l32) ^ lsw) << 4));                                  \
} while (0)

#define MMQ32(ASET, BSET, mh) do {                                             \
  __builtin_amdgcn_s_setprio(1);                                               \
  _Pragma("unroll")                                                            \
  for (int a_ = 0; a_ < 2; ++a_) {                                             \
    _Pragma("unroll")                                                          \
    for (int n_ = 0; n_ < 2; ++n_) {                                           \
      acc[(mh) * 2 + a_][n_] = __builtin_amdgcn_mfma_f32_32x32x16_bf16(        \
          ASET[a_][0], BSET[n_][0], acc[(mh) * 2 + a_][n_], 0, 0, 0);          \
      acc[(mh) * 2 + a_][n_] = __builtin_amdgcn_mfma_f32_32x32x16_bf16(        \
          ASET[a_][1], BSET[n_][1], acc[(mh) * 2 + a_][n_], 0, 0, 0);          \
    }                                                                          \
  }                                                                            \
  __builtin_amdgcn_s_setprio(0);                                               \
} while (0)

__global__ __launch_bounds__(512, 2) void gemm_kernel(
    const unsigned short* __restrict__ xb, const unsigned short* __restrict__ wb,
    const float* __restrict__ bias, const float* __restrict__ inter,
    const float* __restrict__ lb, const int* __restrict__ eid,
    float* __restrict__ out) {
  __shared__ unsigned char smem[131072];

  const int bid = blockIdx.x;
  const int swz = (bid & 7) * 128 + (bid >> 3);   // 1024 wgs, bijective
  const int bm = swz >> 4, bn = swz & 15;         // bm-major (r7 map, best FETCH)
  const int brow = bm * BM, bcol = bn * BN;
  const int t = threadIdx.x;
  const int w = t >> 6, l = t & 63;
  const int wr = w >> 2, wc = w & 3;              // 2 x 4 wave grid, wave = 128x64 out
  const int lhi = (l >> 4) & 1;
  const int l15 = l & 15;
  const int l32 = l >> 5;
  const int lsw = (l >> 1) & 3;

  // staging source (pre-swizzled; inverse of the ds_read swizzle, rule 21).
  // f(row) = (row>>1)&3; GLD row = t>>2  ->  f = (t>>3)&3.
  const int srow = t >> 2;
  const int scol = ((t & 3) ^ ((t >> 3) & 3)) << 3;
  const unsigned short* gA = xb + (size_t)(brow + srow) * K_TOT + scol;
  const unsigned short* gB = wb + (size_t)(bcol + srow) * K_TOT + scol;
  const int ldsw = w << 10;

  f32x16 acc[4][2];
#pragma unroll
  for (int i = 0; i < 4; ++i)
#pragma unroll
    for (int n = 0; n < 2; ++n)
#pragma unroll
      for (int r = 0; r < 16; ++r)
        acc[i][n][r] = 0.f;
  bf16x8 A0[2][2], A1[2][2], B0[2][2], B1[2][2];

  // prologue: tile0 all 4 halves + tile1 {B-k0, A-k0, B-k1}; keep T1's 3
  // halves (6 instr) in flight across the barrier (counted vmcnt).
  STAGE(0, 0, 0); STAGE(1, 0, 0); STAGE(0, 1, 0); STAGE(1, 1, 0);
  STAGE(1, 0, 1); STAGE(0, 0, 1); STAGE(1, 1, 1);
  asm volatile("s_waitcnt vmcnt(6)" ::: "memory");
  BARRIER();

  for (int T = 0; T < NTK; ++T) {
    const int bo = (T & 1) << 16;
    // ph0: A(mh0,k0), B(k0) ; stage A-k1(T+1)
    RD_A32(A0, 0, 0, bo); RD_B32(B0, 0, bo);
    if (T + 1 < NTK) STAGE(0, 1, T + 1);
    BARRIER();
    MMQ32(A0, B0, 0);
    BARRIER();
    // ph1: A(mh1,k0) ; stage B-k0(T+2)
    RD_A32(A1, 1, 0, bo);
    if (T + 2 < NTK) STAGE(1, 0, T + 2);
    BARRIER();
    MMQ32(A1, B0, 1);
    BARRIER();
    // ph2: A(mh0,k1), B(k1) ; stage A-k0(T+2)
    RD_A32(A0, 0, 1, bo); RD_B32(B1, 1, bo);
    if (T + 2 < NTK) STAGE(0, 0, T + 2);
    BARRIER();
    MMQ32(A0, B1, 0);
    BARRIER();
    // ph3: A(mh1,k1) ; stage B-k1(T+2) ; boundary counted vmcnt
    RD_A32(A1, 1, 1, bo);
    if (T + 2 < NTK) STAGE(1, 1, T + 2);
    BARRIER();
    MMQ32(A1, B1, 1);
    if (T + 2 < NTK) { asm volatile("s_waitcnt vmcnt(6)" ::: "memory"); }
    else             { asm volatile("s_waitcnt vmcnt(0)" ::: "memory"); }
    BARRIER();
  }

  // ---------------- epilogue: bias + 2.0 * inter @ lb^T ----------------
  __syncthreads();
  float* interS = reinterpret_cast<float*>(smem);           // 256 x 16 f32 (broadcast)
  float* lbS    = reinterpret_cast<float*>(smem + 16384);   // 256 x 17 f32 (padded)
  const int e = eid[brow >> 11];
  const float* interG = inter + (size_t)brow * RNK;
  const float* lbG    = lb + ((size_t)e * N_TOT + bcol) * RNK;
#pragma unroll
  for (int q = 0; q < 8; ++q) {
    const int idx = t + 512 * q;
    interS[idx] = interG[idx];
    lbS[(idx >> 4) * 17 + (idx & 15)] = lbG[idx];
  }
  __syncthreads();

  // C/D layout (32x32): col = lane&31, row = (r&3) + 8*(r>>2) + 4*(lane>>5)
  const int ccol = wc * 64 + (l & 31);
  float bv[2];
#pragma unroll
  for (int n = 0; n < 2; ++n)
    bv[n] = bias[bcol + ccol + n * 32];

#pragma unroll
  for (int ar = 0; ar < 4; ++ar) {
#pragma unroll
    for (int r = 0; r < 16; ++r) {
      const int ml = wr * 128 + ar * 32 + (r & 3) + 8 * (r >> 2) + 4 * l32;
      const float* iv = interS + ml * RNK;
      const size_t orow = (size_t)(brow + ml) * N_TOT + bcol;
#pragma unroll
      for (int n = 0; n < 2; ++n) {
        const int ol = ccol + n * 32;
        const float* lv = lbS + ol * 17;
        float d = 0.f;
#pragma unroll
        for (int rr = 0; rr < RNK; ++rr) d += iv[rr] * lv[rr];
        out[orow + ol] = acc[ar][n][r] + bv[n] + 2.0f * d;
      }
    }
  }
}

extern "C" void kernel_launch(void* const* d_in, const int* in_sizes, int n_in,
                              void* d_out, int out_size, void* d_ws, size_t ws_size,
                              hipStream_t stream) {
  const float* x    = (const float*)d_in[0];
  const int*   eid  = (const int*)d_in[1];
  const float* W    = (const float*)d_in[2];
  const float* bias = (const float*)d_in[3];
  const float* la   = (const float*)d_in[4];
  const float* lb   = (const float*)d_in[5];
  float* out = (float*)d_out;

  // workspace layout: xb (134MB) | wb (33.5MB) | inter (1MB)
  unsigned short* xb = (unsigned short*)d_ws;
  unsigned short* wb = xb + (size_t)M_TOT * K_TOT;
  float* inter = (float*)(wb + (size_t)N_TOT * K_TOT);

  cvt_f32_bf16<<<2048, 256, 0, stream>>>(W, wb, (N_TOT * K_TOT) / 4);
  xcvt_inter_kernel<<<M_TOT / 8, 256, 0, stream>>>(x, eid, la, xb, inter);

  gemm_kernel<<<(M_TOT / BM) * (N_TOT / BN), 512, 0, stream>>>(
      xb, wb, bias, inter, lb, eid, out);
}